// Round 11
// baseline (379.335 us; speedup 1.0000x reference)
//
#include <hip/hip_runtime.h>
#include <hip/hip_bf16.h>

#define B_     32
#define NL     256
#define NH     16
#define DD     512
#define KK     8
#define LPB    32          // l's per block
#define NLC    8           // l-chunks (= spart slots)
#define CHUNK  4           // l's per softmax barrier
#define PSTR   24          // xs row stride in f16 (16 data + 8 pad)
#define NBLK   256

typedef _Float16 f16;
typedef __attribute__((ext_vector_type(8)))  f16   f16x8;
typedef __attribute__((ext_vector_type(16))) float f32x16;

#define LO_SCALE 1024.0f
#define LO_INV   (1.0f / 1024.0f)

__device__ __forceinline__ void split2s(float f, f16& h, f16& l) {
    h = (f16)f;
    l = (f16)((f - (float)h) * LO_SCALE);
}

// single-use saturating grid barrier (all NBLK blocks co-resident by construction)
__device__ __forceinline__ void gbar(unsigned* cnt, int id) {
    __syncthreads();
    if (threadIdx.x == 0) {
        __threadfence();                                   // release: flush block's stores
        atomicAdd(&cnt[id], 1u);
        while (__hip_atomic_load(&cnt[id], __ATOMIC_RELAXED,
                                 __HIP_MEMORY_SCOPE_AGENT) < NBLK)
            __builtin_amdgcn_s_sleep(2);
        __threadfence();                                   // acquire: invalidate caches
    }
    __syncthreads();
}

// ONE kernel: t2 build -> [iter0 | reduce | iter1 | reduce | iter2 | reduce-out]
// Block = lc*32+b (same-b blocks share an XCD -> spart/vbuf/x XCD-local).
// 16 waves; wave w owns h=w. Per (l,h): P = c00+(c01+c10)/1024 via 3 MFMAs.
__global__ __launch_bounds__(1024, 4)
void fused_kernel(const float* __restrict__ x, const float* __restrict__ W,
                  const float* __restrict__ alpha,
                  f16* __restrict__ t2h, f16* __restrict__ t2l,
                  float* __restrict__ vbuf, float* __restrict__ spart,
                  unsigned* __restrict__ cnt,
                  float* __restrict__ out_v, float* __restrict__ out_a) {
    __shared__ __align__(16) f16 xsh[LPB * 16 * PSTR];   // 24 KB
    __shared__ __align__(16) f16 xsl[LPB * 16 * PSTR];   // 24 KB
    __shared__ float dotsL[2][CHUNK][16];
    __shared__ float blogS[LPB][16];                     // logits, persist iter1->iter2

    const int t  = threadIdx.x;
    const int lc = blockIdx.x >> 5, b = blockIdx.x & 31;  // blk%8 = b%8 = XCD
    const int l0 = lc * LPB;
    const int wv = t >> 6, lane = t & 63;                 // wv = h
    const int o  = lane & 31, l5 = lane >> 5;
    const int i0 = l5 * 8;
    const int rA = lane & 15;

    // ---- phase T: build t2 for l = lc*32+b (inside this block's own read slice) ----
    {
        const int l = lc * 32 + b;
        const int d = t & 511;                 // constant per thread
        float wr[KK];
#pragma unroll
        for (int k = 0; k < KK; ++k) wr[k] = W[k * DD + d];
        const size_t tbase = (size_t)l * NH * DD + ((d & 31) * 16 + (d >> 5));
#pragma unroll
        for (int e = 0; e < 8; ++e) {
            const int h = 2 * e + (t >> 9);
            const float* al = alpha + ((size_t)l * NH + h) * KK;
            float acc = 0.f;
#pragma unroll
            for (int k = 0; k < KK; ++k) acc = fmaf(al[k], wr[k], acc);
            f16 hh, ll; split2s(acc, hh, ll);
            t2h[tbase + (size_t)h * DD] = hh;
            t2l[tbase + (size_t)h * DD] = ll;
        }
    }

    // ---- stage x once: xs[(l*16+r)*PSTR + i] ----
    {
        const int row = t >> 1, half = t & 1;
        const float* xg = x + ((size_t)b * NL + l0 + (row >> 4)) * 256
                            + (row & 15) * 16 + half * 8;
        float xv[8];
        *(float4*)&xv[0] = *(const float4*)&xg[0];
        *(float4*)&xv[4] = *(const float4*)&xg[4];
        f16 hi[8], lo[8];
#pragma unroll
        for (int j = 0; j < 8; ++j) split2s(xv[j], hi[j], lo[j]);
        const int la = row * PSTR + half * 8;
        *(f16x8*)&xsh[la] = *(f16x8*)&hi[0];
        *(f16x8*)&xsl[la] = *(f16x8*)&lo[0];
    }
    gbar(cnt, 0);                                        // t2 ready everywhere

    for (int it = 0; it < 3; ++it) {
        // ---- v preload (it>0): vr[j] = v[b,wv, rr(j)*32+o] ----
        float vr[8];
        if (it > 0) {
            const float* vp = vbuf + ((size_t)b * NH + wv) * DD;
#pragma unroll
            for (int j = 0; j < 8; ++j) {
                const int rr = (j & 3) + 8 * (j >> 2) + 4 * l5;
                vr[j] = vp[rr * 32 + o];
            }
        }

        f16x8 pf0, pf1;
        {
            const size_t tb = ((size_t)l0 * NH + wv) * DD + o * 16 + i0;
            pf0 = *(const f16x8*)(t2h + tb);
            pf1 = *(const f16x8*)(t2l + tb);
        }

        float sacc[8];
#pragma unroll
        for (int j = 0; j < 8; ++j) sacc[j] = 0.f;

        for (int ch = 0; ch < LPB / CHUNK; ++ch) {
            const int par = ch & 1;
            float Pst[CHUNK][8];
#pragma unroll
            for (int lq = 0; lq < CHUNK; ++lq) {
                const int l = ch * CHUNK + lq;
                const int la = (l * 16 + rA) * PSTR + i0;
                const f16x8 a0 = *(const f16x8*)&xsh[la];
                const f16x8 a1 = *(const f16x8*)&xsl[la];
                const f16x8 c0 = pf0, c1 = pf1;
                if (l + 1 < LPB) {
                    const size_t tb = ((size_t)(l0 + l + 1) * NH + wv) * DD + o * 16 + i0;
                    pf0 = *(const f16x8*)(t2h + tb);
                    pf1 = *(const f16x8*)(t2l + tb);
                }
                f32x16 z;
#pragma unroll
                for (int j = 0; j < 16; ++j) z[j] = 0.f;
                f32x16 c00 = __builtin_amdgcn_mfma_f32_32x32x16_f16(a0, c0, z, 0, 0, 0);
                f32x16 c01 = __builtin_amdgcn_mfma_f32_32x32x16_f16(a0, c1, z, 0, 0, 0);
                f32x16 c10 = __builtin_amdgcn_mfma_f32_32x32x16_f16(a1, c0, z, 0, 0, 0);
                float d0 = 0.f;
#pragma unroll
                for (int j = 0; j < 8; ++j) {
                    const float pj = fmaf(c01[j] + c10[j], LO_INV, c00[j]);
                    if (it != 0) { Pst[lq][j] = pj; d0 = fmaf(pj, vr[j], d0); }
                    else         sacc[j] += pj;
                }
                if (it != 0) {
#pragma unroll
                    for (int mm = 1; mm < 64; mm <<= 1) d0 += __shfl_xor(d0, mm, 64);
                    if (lane == 0) dotsL[par][lq][wv] = d0;
                }
            }

            if (it != 0) {
                __syncthreads();        // dotsL[par] published
                // wave-local softmax: lane -> (lq = lane>>4, hq = lane&15)
                const int lql = lane >> 4, hq = lane & 15;
                float d = dotsL[par][lql][hq];
                if (it == 2) d += blogS[ch * CHUNK + lql][hq];
                if (it == 1 && wv == 0) blogS[ch * CHUNK + lql][hq] = d;
                float mx = d;
#pragma unroll
                for (int mm = 1; mm < 16; mm <<= 1) mx = fmaxf(mx, __shfl_xor(mx, mm, 16));
                const float e = __expf(d - mx);
                float sm = e;
#pragma unroll
                for (int mm = 1; mm < 16; mm <<= 1) sm += __shfl_xor(sm, mm, 16);
                const float cv = e / sm;
#pragma unroll
                for (int lq = 0; lq < CHUNK; ++lq) {
                    const float c = __shfl(cv, lq * 16 + wv, 64);
#pragma unroll
                    for (int j = 0; j < 8; ++j)
                        sacc[j] = fmaf(c, Pst[lq][j], sacc[j]);
                }
            }
        }

        // ---- store partial s: spart[lc][b][wv][rr*32+o] (plain, XCD-local) ----
        {
            float* sp = spart + ((size_t)lc * (B_ * NH) + b * NH + wv) * DD;
#pragma unroll
            for (int j = 0; j < 8; ++j) {
                const int rr = (j & 3) + 8 * (j >> 2) + 4 * l5;
                sp[rr * 32 + o] = sacc[j];
            }
        }
        gbar(cnt, 1 + 2 * it);                 // all partials visible

        // ---- reduce + squash: waves 0,1 handle (b, h = lc*2 + wv) ----
        if (wv < 2) {
            const int h  = lc * 2 + wv;
            const int bh = b * NH + h;
            const float cs = (it == 0) ? (1.0f / 16.0f) : 1.0f;
            float acc[8];
#pragma unroll
            for (int j = 0; j < 8; ++j) acc[j] = 0.f;
            for (int ls = 0; ls < NLC; ++ls) {             // fixed order
                const float* p = spart + ((size_t)ls * (B_ * NH) + bh) * DD + lane * 8;
                const float4 u0 = *(const float4*)&p[0];
                const float4 u1 = *(const float4*)&p[4];
                acc[0] += u0.x; acc[1] += u0.y; acc[2] += u0.z; acc[3] += u0.w;
                acc[4] += u1.x; acc[5] += u1.y; acc[6] += u1.z; acc[7] += u1.w;
            }
#pragma unroll
            for (int j = 0; j < 8; ++j) acc[j] *= cs;
            float sq = 0.f;
#pragma unroll
            for (int j = 0; j < 8; ++j) sq = fmaf(acc[j], acc[j], sq);
#pragma unroll
            for (int mm = 1; mm < 64; mm <<= 1) sq += __shfl_xor(sq, mm, 64);
            const float scale = sq / (1.0f + sq);
            const float inv   = scale / sqrtf(sq + 1e-11f);
            float* po = (it == 2) ? (out_v + (size_t)bh * DD + lane * 8)
                                  : (vbuf + (size_t)bh * DD + lane * 8);
#pragma unroll
            for (int j = 0; j < 8; ++j) po[j] = acc[j] * inv;
            if (it == 2 && lane == 0) out_a[bh] = scale;
        }
        if (it < 2) gbar(cnt, 2 + 2 * it);     // v visible before next iteration
    }
}

extern "C" void kernel_launch(void* const* d_in, const int* in_sizes, int n_in,
                              void* d_out, int out_size, void* d_ws, size_t ws_size,
                              hipStream_t stream) {
    const float* x     = (const float*)d_in[0];
    // d_in[1] = adj (unused by forward)
    const float* W     = (const float*)d_in[2];
    const float* alpha = (const float*)d_in[3];
    float* out   = (float*)d_out;
    float* out_v = out;                          // B*NH*DD
    float* out_a = out + (size_t)B_ * NH * DD;   // B*NH

    char* base = (char*)d_ws;
    size_t off = 0;
    f16*      t2h   = (f16*)(base + off);      off += (size_t)NL * NH * DD * 2;       // 4 MB
    f16*      t2l   = (f16*)(base + off);      off += (size_t)NL * NH * DD * 2;       // 4 MB
    float*    spart = (float*)(base + off);    off += (size_t)NLC * B_ * NH * DD * 4; // 8 MB
    float*    vbuf  = (float*)(base + off);    off += (size_t)B_ * NH * DD * 4;       // 1 MB
    unsigned* cnt   = (unsigned*)(base + off); off += 64;                             // ~17 MB

    hipMemsetAsync(cnt, 0, 64, stream);          // reset barrier counters every launch

    fused_kernel<<<NBLK, 1024, 0, stream>>>(x, W, alpha, t2h, t2l,
                                            vbuf, spart, cnt, out_v, out_a);
}